// Round 7
// baseline (701.147 us; speedup 1.0000x reference)
//
#include <hip/hip_runtime.h>
#include <math.h>

#define K_EMB 1024
#define D_DIM 256
#define T_SZ 2048
#define TOT 16777216        // B*D*T
#define LOSS_OFF 16777216
#define IDX_OFF 16777217
#define NDC 17              // 16 real d-chunks + 1 esq-fold chunk (A-side)
#define THR 0.6f            // ~8.5 sigma of bf16 score-diff noise -> exact refine

// workspace layout (bytes) — 1,867,776 total
#define WS_EHI  0           //   557,056  E frags [32 kc][17 dc][64 lane] x 16B
#define WS_X2   557056      //   262,144  ||x||^2 per token [65536] f32
#define WS_CAND 819200      // 1,048,576  per-token top3 packed float4 [65536]

// K2 (argmin) LDS layout
#define SM2_XH  0           // 65,536  X frags for the 128-t tile
#define SM2_X2P 65536       //  4,096  per-thread x^2 partials (1024 f32)
#define SM2_RV  69632       // 24,576  top3 vals [16w][4tc][32m][3] f32
#define SM2_RK  94208       // 24,576  top3 keys
#define SM2_TOT 118784      // -> 1 block/CU

// K3 (finish) LDS layout
#define SM3_Q    0          // 65,792  q overlay [64][257] f32 (conflict-free cols)
#define SM3_IDX  65792      //    256  idx per t
#define SM3_TIEC 66048      //      8  tie count
#define SM3_TIEL 66056      //    512  64 x uint2 tie entries
#define SM3_TOT  66568      // -> 2 blocks/CU

typedef __attribute__((ext_vector_type(8)))  __bf16 bf16x8;
typedef __attribute__((ext_vector_type(8)))  short  s16x8;
typedef __attribute__((ext_vector_type(16))) float  f32x16;

__device__ __forceinline__ unsigned short f2bf(float f) {   // RNE fp32->bf16 bits
    unsigned u = __float_as_uint(f);
    u += 0x7FFFu + ((u >> 16) & 1u);
    return (unsigned short)(u >> 16);
}
__device__ __forceinline__ float bf2f(unsigned short h) {
    return __uint_as_float(((unsigned)h) << 16);
}
// top-3 insert, maximizing, tie -> smaller k. Insertion-order-safe.
__device__ __forceinline__ void ins3(float& v1, int& k1, float& v2, int& k2,
                                     float& v3, int& k3, float v, int k) {
    bool b1 = (v > v1) || (v == v1 && k < k1);
    bool b2 = (v > v2) || (v == v2 && k < k2);
    bool b3 = (v > v3) || (v == v3 && k < k3);
    if (b1)      { v3 = v2; k3 = k2; v2 = v1; k2 = k1; v1 = v; k1 = k; }
    else if (b2) { v3 = v2; k3 = k2; v2 = v;  k2 = k; }
    else if (b3) { v3 = v;  k3 = k; }
}

// --- K0: pre-pack E into MFMA A-frag order (bf16) + loss zero -------------
// frag (kc, dc, lane): A[m=lane&31][kd=(lane>>5)*8+j], k=kc*32+m,
// d=dc*16+(lane>>5)*8+j. dc==16 = esq-fold: slot0=bf16(-esq/2), slot1=residual.
__global__ __launch_bounds__(256) void prepack_kernel(const float* __restrict__ E,
        unsigned short* __restrict__ Ehi, float* __restrict__ loss) {
    if (blockIdx.x == 0 && threadIdx.x == 0) loss[0] = 0.f;
    int gid = blockIdx.x * 256 + threadIdx.x;        // == (kc*17+dc)*64 + lane
    if (gid >= 32 * NDC * 64) return;
    int lane = gid & 63;
    int dc = (gid >> 6) % NDC;
    int kc = gid / (NDC * 64);
    int m = lane & 31, dh = lane >> 5;
    int k = kc * 32 + m;
    unsigned short h8[8];
#pragma unroll
    for (int j = 0; j < 8; ++j) h8[j] = 0;
    if (dc < 16) {
        int d0 = dc * 16 + dh * 8;
        const float* ep = E + (size_t)k * D_DIM + d0;
#pragma unroll
        for (int j = 0; j < 8; ++j) h8[j] = f2bf(ep[j]);
    } else if (dh == 0) {
        const float* er = E + (size_t)k * D_DIM;
        float s0 = 0.f, s1 = 0.f, s2 = 0.f, s3 = 0.f;
        for (int i = 0; i < D_DIM; i += 4) {
            s0 = fmaf(er[i], er[i], s0);
            s1 = fmaf(er[i + 1], er[i + 1], s1);
            s2 = fmaf(er[i + 2], er[i + 2], s2);
            s3 = fmaf(er[i + 3], er[i + 3], s3);
        }
        float v = -0.5f * ((s0 + s1) + (s2 + s3));
        unsigned short h = f2bf(v);
        h8[0] = h;
        h8[1] = f2bf(v - bf2f(h));
    }
    s16x8 hv;
#pragma unroll
    for (int j = 0; j < 8; ++j) hv[j] = (short)h8[j];
    ((s16x8*)Ehi)[gid] = hv;
}

// --- K2: argmin core. grid 512 (2 rounds of 1 block/CU), 1024 thr/16 waves -
// Stages X tile [128 t][256 d] -> frag-order bf16 LDS (coalesced: lanes span
// t). Wave w owns kc = kcg*16+w per pass (2 passes): acc[4 tc] f32x16 = 64
// AGPR. Per 1KB E-frag: 4 MFMAs; E read ONCE per block (544 KB, L2-resident).
// Output: per-token ||x||^2 and packed top3 (v1,v2,v3,keys).
__global__ __launch_bounds__(1024) void argmin_kernel(
        const float* __restrict__ X, const unsigned short* __restrict__ Ehi,
        float4* __restrict__ cand, float* __restrict__ x2g) {
    extern __shared__ char smem[];
    unsigned short* xhf = (unsigned short*)(smem + SM2_XH);
    float* x2p = (float*)(smem + SM2_X2P);
    float* redv = (float*)(smem + SM2_RV);
    int*   redk = (int*)(smem + SM2_RK);

    int tid = threadIdx.x;
    int lane = tid & 63;
    int w = tid >> 6;                        // 0..15
    int dhalf = lane >> 5;
    int tile = blockIdx.x;                   // 0..511
    int b = tile >> 4, tg0 = (tile & 15) << 7;

    // ---- stage X tile -> frag-order bf16 in LDS + ||x||^2 partials ----
    {
        int t = tid & 127, dblk = tid >> 7;  // 8 dblk x 32 d
        int tc = t >> 5, m = t & 31;
        const float* xp = X + (size_t)b * ((size_t)D_DIM * T_SZ) + tg0 + t;
        float x2a = 0.f;
#pragma unroll
        for (int g = 0; g < 4; ++g) {
            int d0 = dblk * 32 + g * 8;
            s16x8 hv;
#pragma unroll
            for (int j = 0; j < 8; ++j) {
                float xv = xp[(size_t)(d0 + j) * T_SZ];
                hv[j] = (short)f2bf(xv);
                x2a = fmaf(xv, xv, x2a);
            }
            int fi = (tc * 16 + (d0 >> 4)) * 64 + ((d0 >> 3) & 1) * 32 + m;
            ((s16x8*)xhf)[fi] = hv;
        }
        x2p[tid] = x2a;
    }
    __syncthreads();

    const s16x8* ehp = (const s16x8*)Ehi;
    const s16x8* bhf = (const s16x8*)xhf;

    s16x8 bfold = {0, 0, 0, 0, 0, 0, 0, 0};
    if (dhalf == 0) { bfold[0] = (short)0x3F80; bfold[1] = (short)0x3F80; }
    bf16x8 bh_fold = __builtin_bit_cast(bf16x8, bfold);

    float v1s[4], v2s[4], v3s[4];
    int k1s[4], k2s[4], k3s[4];
#pragma unroll
    for (int j = 0; j < 4; ++j) { v1s[j] = -INFINITY; v2s[j] = -INFINITY;
                                  v3s[j] = -INFINITY; k1s[j] = 0; k2s[j] = 0;
                                  k3s[j] = 0; }

#pragma unroll 1
    for (int kcg = 0; kcg < 2; ++kcg) {
        int kc = kcg * 16 + w;               // this wave's codebook tile
        f32x16 acc[4];
#pragma unroll
        for (int tc = 0; tc < 4; ++tc)
#pragma unroll
            for (int i = 0; i < 16; ++i) acc[tc][i] = 0.f;

        size_t ab = (size_t)kc * NDC * 64 + lane;
        s16x8 nh = ehp[ab];                  // depth-1 rotating prefetch

#pragma unroll 1
        for (int dc = 0; dc < 16; ++dc) {
            bf16x8 ah = __builtin_bit_cast(bf16x8, nh);
            nh = ehp[ab + (size_t)(dc + 1) * 64];    // dc==15 -> fold chunk
#pragma unroll
            for (int tc = 0; tc < 4; ++tc) {
                bf16x8 bh = __builtin_bit_cast(bf16x8, bhf[(tc * 16 + dc) * 64 + lane]);
                acc[tc] = __builtin_amdgcn_mfma_f32_32x32x16_bf16(ah, bh, acc[tc], 0, 0, 0);
            }
        }
        {   // esq-fold chunk (prefetched): B constant 1.0 in kd slots 0,1
            bf16x8 ah = __builtin_bit_cast(bf16x8, nh);
#pragma unroll
            for (int tc = 0; tc < 4; ++tc)
                acc[tc] = __builtin_amdgcn_mfma_f32_32x32x16_bf16(ah, bh_fold, acc[tc], 0, 0, 0);
        }
        // scan acc -> per-tc running top3 (insertion-order-safe)
        int kb = kc * 32 + 4 * dhalf;
#pragma unroll
        for (int tc = 0; tc < 4; ++tc)
#pragma unroll
            for (int r = 0; r < 16; ++r) {
                int kk = kb + (r & 3) + 8 * (r >> 2);
                ins3(v1s[tc], k1s[tc], v2s[tc], k2s[tc],
                     v3s[tc], k3s[tc], acc[tc][r], kk);
            }
    }

    // merge lane^32 partner (same t, complementary k rows), store to LDS
#pragma unroll
    for (int tc = 0; tc < 4; ++tc) {
        float pv1 = __shfl_xor(v1s[tc], 32, 64); int pk1 = __shfl_xor(k1s[tc], 32, 64);
        float pv2 = __shfl_xor(v2s[tc], 32, 64); int pk2 = __shfl_xor(k2s[tc], 32, 64);
        float pv3 = __shfl_xor(v3s[tc], 32, 64); int pk3 = __shfl_xor(k3s[tc], 32, 64);
        ins3(v1s[tc], k1s[tc], v2s[tc], k2s[tc], v3s[tc], k3s[tc], pv1, pk1);
        ins3(v1s[tc], k1s[tc], v2s[tc], k2s[tc], v3s[tc], k3s[tc], pv2, pk2);
        ins3(v1s[tc], k1s[tc], v2s[tc], k2s[tc], v3s[tc], k3s[tc], pv3, pk3);
        if (dhalf == 0) {
            int base = ((w * 4 + tc) * 32 + (lane & 31)) * 3;
            redv[base]     = v1s[tc]; redk[base]     = k1s[tc];
            redv[base + 1] = v2s[tc]; redk[base + 1] = k2s[tc];
            redv[base + 2] = v3s[tc]; redk[base + 2] = k3s[tc];
        }
    }
    __syncthreads();

    // per-t reduce across 16 waves -> packed top3 + ||x||^2 to global
    if (tid < 128) {
        int t = tid, tc = t >> 5, m = t & 31;
        float v1 = -INFINITY, v2 = -INFINITY, v3 = -INFINITY;
        int k1 = 0, k2 = 0, k3 = 0;
#pragma unroll
        for (int ww = 0; ww < 16; ++ww) {
            int base = ((ww * 4 + tc) * 32 + m) * 3;
            ins3(v1, k1, v2, k2, v3, k3, redv[base], redk[base]);
            ins3(v1, k1, v2, k2, v3, k3, redv[base + 1], redk[base + 1]);
            ins3(v1, k1, v2, k2, v3, k3, redv[base + 2], redk[base + 2]);
        }
        float x2 = 0.f;
#pragma unroll
        for (int i = 0; i < 8; ++i) x2 += x2p[t + 128 * i];
        x2g[(size_t)tile * 128 + t] = x2;
        unsigned bits = (unsigned)k1 | ((unsigned)k2 << 10) | ((unsigned)k3 << 20);
        cand[(size_t)tile * 128 + t] =
            make_float4(v1, v2, v3, __int_as_float((int)bits));
    }
}

// --- K3: finish. grid 1024 x 256 thr, t-tile 64, 2 blocks/CU --------------
// reduce cand -> idx/loss (ties -> wave-parallel exact fp64 over top-3),
// gather E rows into LDS, write out0 [B,D,T] + idx.
__global__ __launch_bounds__(256) void finish_kernel(
        const float* __restrict__ X, const float* __restrict__ E,
        const float4* __restrict__ cand, const float* __restrict__ x2g,
        float* __restrict__ out0, float* __restrict__ loss,
        float* __restrict__ idxf_out) {
    extern __shared__ char smem[];
    float* q    = (float*)(smem + SM3_Q);    // [64][257]
    int*   idxs = (int*)(smem + SM3_IDX);
    int*   tiec = (int*)(smem + SM3_TIEC);
    uint2* tiel = (uint2*)(smem + SM3_TIEL);

    int tid = threadIdx.x;
    int lane = tid & 63;
    int w = tid >> 6;                        // 0..3
    int b = blockIdx.x >> 5;                 // 0..31
    int tg0 = (blockIdx.x & 31) << 6;
    size_t n0 = (size_t)blockIdx.x * 64;     // global token base

    if (tid == 0) tiec[0] = 0;
    __syncthreads();

    if (tid < 64) {
        int t = tid;
        float4 c = cand[n0 + t];
        int bits = __float_as_int(c.w);
        int k1 = bits & 1023, k2 = (bits >> 10) & 1023, k3 = (bits >> 20) & 1023;
        float dmin2 = 0.f;
        if (c.x - c.y < THR) {    // near-tie: defer exact fp64 refinement
            int slot = atomicAdd(tiec, 1);
            tiel[slot] = make_uint2(((unsigned)t << 10) | (unsigned)k1,
                                    ((unsigned)k2 << 16) | (unsigned)k3);
        } else {
            idxs[t] = k1;
            idxf_out[(size_t)b * T_SZ + tg0 + t] = (float)k1;
            dmin2 = x2g[n0 + t] - 2.0f * c.x;   // ||x||^2 - 2(x.e - esq/2)
        }
        float lsum = dmin2;
#pragma unroll
        for (int off = 32; off > 0; off >>= 1) lsum += __shfl_down(lsum, off, 64);
        if (tid == 0) atomicAdd(loss, lsum * (0.5f / (float)TOT));
    }
    __syncthreads();

    // wave-parallel exact refinement: one wave per tie, 64 lanes x 4 d each
    {
        int ntie = tiec[0];
        for (int e = w; e < ntie; e += 4) {
            uint2 pk = tiel[e];
            int t = pk.x >> 10;
            int k1 = pk.x & 1023, k2 = pk.y >> 16, k3 = pk.y & 1023;
            const float* e1 = E + (size_t)k1 * D_DIM;
            const float* e2 = E + (size_t)k2 * D_DIM;
            const float* e3 = E + (size_t)k3 * D_DIM;
            const float* xc = X + (size_t)b * ((size_t)D_DIM * T_SZ) + tg0 + t;
            int d0 = lane * 4;
            double d1 = 0.0, d2 = 0.0, d3 = 0.0;
#pragma unroll
            for (int u = 0; u < 4; ++u) {
                int d = d0 + u;
                double xd = (double)xc[(size_t)d * T_SZ];
                double u1 = xd - (double)e1[d];
                double u2 = xd - (double)e2[d];
                double u3 = xd - (double)e3[d];
                d1 += u1 * u1;
                d2 += u2 * u2;
                d3 += u3 * u3;
            }
#pragma unroll
            for (int off = 32; off > 0; off >>= 1) {
                d1 += __shfl_down(d1, off, 64);
                d2 += __shfl_down(d2, off, 64);
                d3 += __shfl_down(d3, off, 64);
            }
            if (lane == 0) {
                int kb = k1; double dm = d1;
                if (d2 < dm || (d2 == dm && k2 < kb)) { kb = k2; dm = d2; }
                if (d3 < dm || (d3 == dm && k3 < kb)) { kb = k3; dm = d3; }
                idxs[t] = kb;
                idxf_out[(size_t)b * T_SZ + tg0 + t] = (float)kb;
                atomicAdd(loss, (float)dm * (0.5f / (float)TOT));
            }
        }
    }
    __syncthreads();

    // gather E rows into q overlay (stride 257 -> conflict-free column reads)
    {
        for (int i = 0; i < 16; ++i) {
            int r = w * 16 + i;
            int row = idxs[r];
            const float* ep = E + (size_t)row * D_DIM;
#pragma unroll
            for (int u = 0; u < 4; ++u)
                q[r * 257 + lane + 64 * u] = ep[lane + 64 * u];
        }
    }
    __syncthreads();

    // write out0 [B,D,T]: lanes over t (coalesced 256B), LDS conflict-free
    {
        int t = tid & 63, dgrp = tid >> 6;
        size_t obase = (size_t)b * ((size_t)D_DIM * T_SZ) + tg0 + t;
#pragma unroll 8
        for (int j = 0; j < 64; ++j) {
            int d = dgrp * 64 + j;
            out0[obase + (size_t)d * T_SZ] = q[t * 257 + d];
        }
    }
}

extern "C" void kernel_launch(void* const* d_in, const int* in_sizes, int n_in,
                              void* d_out, int out_size, void* d_ws, size_t ws_size,
                              hipStream_t stream) {
    const float* X = (const float*)d_in[0];   // [32, 256, 2048] fp32
    const float* E = (const float*)d_in[1];   // [1024, 256] fp32
    float* out = (float*)d_out;
    float* loss = out + LOSS_OFF;
    float* idxf = out + IDX_OFF;

    unsigned short* Ehi = (unsigned short*)((char*)d_ws + WS_EHI);
    float*          x2g = (float*)((char*)d_ws + WS_X2);
    float4*        candp = (float4*)((char*)d_ws + WS_CAND);

    prepack_kernel<<<(32 * NDC * 64 + 255) / 256, 256, 0, stream>>>(E, Ehi, loss);
    argmin_kernel<<<512, 1024, SM2_TOT, stream>>>(X, Ehi, candp, x2g);
    finish_kernel<<<1024, 256, SM3_TOT, stream>>>(X, E, candp, x2g, out, loss, idxf);
}

// Round 8
// 673.942 us; speedup vs baseline: 1.0404x; 1.0404x over previous
//
#include <hip/hip_runtime.h>
#include <math.h>

#define K_EMB 1024
#define D_DIM 256
#define T_SZ 2048
#define TOT 16777216        // B*D*T
#define LOSS_OFF 16777216
#define IDX_OFF 16777217
#define NDC 17              // 16 real d-chunks + 1 esq-fold chunk (A-side)
#define THR 0.6f            // ~10 sigma of bf16 score-diff noise -> exact refine

// workspace layout (bytes) — 1,867,776 total
#define WS_EHI  0           //   557,056  E frags [32 kc][17 dc][64 lane] x 16B
#define WS_X2   557056      //   262,144  ||x||^2 per token [65536] f32
#define WS_CAND 819200      // 1,048,576  per-token top3 packed float4 [65536]

// K2 (argmin) LDS layout — 92,160 B > 80 KB -> exactly 1 block/CU
#define SM2_XH  0           // 65,536  X frags for the 128-t tile
#define SM2_X2P 65536       //  2,048  per-thread x^2 partials (512 f32)
#define SM2_RV  67584       // 12,288  top3 vals [8w][4tc][32m][3] f32
#define SM2_RK  79872       // 12,288  top3 keys
#define SM2_TOT 92160

// K3 (finish) LDS layout
#define SM3_Q    0          // 65,792  q overlay [64][257] f32 (conflict-free cols)
#define SM3_IDX  65792      //    256  idx per t
#define SM3_TIEC 66048      //      8  tie count
#define SM3_TIEL 66056      //    512  64 x uint2 tie entries
#define SM3_TOT  66568      // -> 2 blocks/CU

typedef __attribute__((ext_vector_type(8)))  __bf16 bf16x8;
typedef __attribute__((ext_vector_type(8)))  short  s16x8;
typedef __attribute__((ext_vector_type(16))) float  f32x16;

__device__ __forceinline__ unsigned short f2bf(float f) {   // RNE fp32->bf16 bits
    unsigned u = __float_as_uint(f);
    u += 0x7FFFu + ((u >> 16) & 1u);
    return (unsigned short)(u >> 16);
}
__device__ __forceinline__ float bf2f(unsigned short h) {
    return __uint_as_float(((unsigned)h) << 16);
}
// top-3 insert, maximizing, VALUE-ONLY compares. Exact-equal scores have
// gap 0 < THR and always route to the exact-fp64 refine (which applies the
// k-tie-break), so tie clauses here are unnecessary. Insertion-order-safe
// for the final answer by the same argument.
__device__ __forceinline__ void ins3(float& v1, int& k1, float& v2, int& k2,
                                     float& v3, int& k3, float v, int k) {
    if (v > v1)      { v3 = v2; k3 = k2; v2 = v1; k2 = k1; v1 = v; k1 = k; }
    else if (v > v2) { v3 = v2; k3 = k2; v2 = v;  k2 = k; }
    else if (v > v3) { v3 = v;  k3 = k; }
}

// --- K0: pre-pack E into MFMA A-frag order (bf16) + loss zero -------------
// frag (kc, dc, lane): A[m=lane&31][kd=(lane>>5)*8+j], k=kc*32+m,
// d=dc*16+(lane>>5)*8+j. dc==16 = esq-fold: slot0=bf16(-esq/2), slot1=residual.
__global__ __launch_bounds__(256) void prepack_kernel(const float* __restrict__ E,
        unsigned short* __restrict__ Ehi, float* __restrict__ loss) {
    if (blockIdx.x == 0 && threadIdx.x == 0) loss[0] = 0.f;
    int gid = blockIdx.x * 256 + threadIdx.x;        // == (kc*17+dc)*64 + lane
    if (gid >= 32 * NDC * 64) return;
    int lane = gid & 63;
    int dc = (gid >> 6) % NDC;
    int kc = gid / (NDC * 64);
    int m = lane & 31, dh = lane >> 5;
    int k = kc * 32 + m;
    unsigned short h8[8];
#pragma unroll
    for (int j = 0; j < 8; ++j) h8[j] = 0;
    if (dc < 16) {
        int d0 = dc * 16 + dh * 8;
        const float* ep = E + (size_t)k * D_DIM + d0;
#pragma unroll
        for (int j = 0; j < 8; ++j) h8[j] = f2bf(ep[j]);
    } else if (dh == 0) {
        const float* er = E + (size_t)k * D_DIM;
        float s0 = 0.f, s1 = 0.f, s2 = 0.f, s3 = 0.f;
        for (int i = 0; i < D_DIM; i += 4) {
            s0 = fmaf(er[i], er[i], s0);
            s1 = fmaf(er[i + 1], er[i + 1], s1);
            s2 = fmaf(er[i + 2], er[i + 2], s2);
            s3 = fmaf(er[i + 3], er[i + 3], s3);
        }
        float v = -0.5f * ((s0 + s1) + (s2 + s3));
        unsigned short h = f2bf(v);
        h8[0] = h;
        h8[1] = f2bf(v - bf2f(h));
    }
    s16x8 hv;
#pragma unroll
    for (int j = 0; j < 8; ++j) hv[j] = (short)h8[j];
    ((s16x8*)Ehi)[gid] = hv;
}

// --- K2: argmin core. grid 512, 512 thr / 8 waves, __launch_bounds__(512,2)
// SPILL-PROOF BY CONSTRUCTION: 2 waves/SIMD -> 256-reg budget; peak live
// state ~150 regs (acc[4]=64, top3=24, bh cur+next=32, E prefetch=12, addr).
// Prior rounds all ran 1024-thr (128-reg cap) and spilled the accumulator to
// scratch (R7: 200 MB HBM write excess = the stall of every round).
// Wave w owns kc = rnd*8+w over 4 rounds; per 1KB E-frag: 4 MFMAs.
__global__ __launch_bounds__(512, 2) void argmin_kernel(
        const float* __restrict__ X, const unsigned short* __restrict__ Ehi,
        float4* __restrict__ cand, float* __restrict__ x2g) {
    extern __shared__ char smem[];
    unsigned short* xhf = (unsigned short*)(smem + SM2_XH);
    float* x2p = (float*)(smem + SM2_X2P);
    float* redv = (float*)(smem + SM2_RV);
    int*   redk = (int*)(smem + SM2_RK);

    int tid = threadIdx.x;
    int lane = tid & 63;
    int w = tid >> 6;                        // 0..7
    int dhalf = lane >> 5;
    int tile = blockIdx.x;                   // 0..511
    int b = tile >> 4, tg0 = (tile & 15) << 7;

    // ---- stage X tile [128 t][256 d] -> frag-order bf16 + ||x||^2 ----
    {
        int t = tid & 127, dblk = tid >> 7;  // 4 dblk x 64 d
        int tc = t >> 5, m = t & 31;
        const float* xp = X + (size_t)b * ((size_t)D_DIM * T_SZ) + tg0 + t;
        float x2a = 0.f;
#pragma unroll
        for (int g = 0; g < 8; ++g) {
            int d0 = dblk * 64 + g * 8;
            s16x8 hv;
#pragma unroll
            for (int j = 0; j < 8; ++j) {
                float xv = xp[(size_t)(d0 + j) * T_SZ];
                hv[j] = (short)f2bf(xv);
                x2a = fmaf(xv, xv, x2a);
            }
            int fi = (tc * 16 + (d0 >> 4)) * 64 + ((d0 >> 3) & 1) * 32 + m;
            ((s16x8*)xhf)[fi] = hv;
        }
        x2p[tid] = x2a;
    }
    __syncthreads();

    const s16x8* ehp = (const s16x8*)Ehi;
    const s16x8* bhf = (const s16x8*)xhf;

    s16x8 bfold = {0, 0, 0, 0, 0, 0, 0, 0};
    if (dhalf == 0) { bfold[0] = (short)0x3F80; bfold[1] = (short)0x3F80; }
    bf16x8 bh_fold = __builtin_bit_cast(bf16x8, bfold);

    float v1s[4], v2s[4], v3s[4];
    int k1s[4], k2s[4], k3s[4];
#pragma unroll
    for (int j = 0; j < 4; ++j) { v1s[j] = -INFINITY; v2s[j] = -INFINITY;
                                  v3s[j] = -INFINITY; k1s[j] = 0; k2s[j] = 0;
                                  k3s[j] = 0; }

#pragma unroll 1
    for (int rnd = 0; rnd < 4; ++rnd) {
        int kc = rnd * 8 + w;                // this wave's codebook tile
        f32x16 acc[4];
#pragma unroll
        for (int tc = 0; tc < 4; ++tc)
#pragma unroll
            for (int i = 0; i < 16; ++i) acc[tc][i] = 0.f;

        size_t ab = (size_t)kc * NDC * 64 + lane;
        s16x8 nh0 = ehp[ab];                 // depth-2 rotating E prefetch
        s16x8 nh1 = ehp[ab + 64];
        s16x8 bc0 = bhf[lane];               // depth-1 bh prefetch (dc=0)
        s16x8 bc1 = bhf[(16 << 6) + lane];
        s16x8 bc2 = bhf[(32 << 6) + lane];
        s16x8 bc3 = bhf[(48 << 6) + lane];

#pragma unroll 1
        for (int dc = 0; dc < 16; ++dc) {
            bf16x8 ah = __builtin_bit_cast(bf16x8, nh0);
            nh0 = nh1;
            int dn = dc + 2; if (dn > 16) dn = 16;     // redundant re-load ok
            nh1 = ehp[ab + (size_t)dn * 64];
            int db = dc + 1; if (db > 15) db = 15;
            s16x8 nb0 = bhf[(db << 6) + lane];
            s16x8 nb1 = bhf[((16 + db) << 6) + lane];
            s16x8 nb2 = bhf[((32 + db) << 6) + lane];
            s16x8 nb3 = bhf[((48 + db) << 6) + lane];
            acc[0] = __builtin_amdgcn_mfma_f32_32x32x16_bf16(
                         ah, __builtin_bit_cast(bf16x8, bc0), acc[0], 0, 0, 0);
            acc[1] = __builtin_amdgcn_mfma_f32_32x32x16_bf16(
                         ah, __builtin_bit_cast(bf16x8, bc1), acc[1], 0, 0, 0);
            acc[2] = __builtin_amdgcn_mfma_f32_32x32x16_bf16(
                         ah, __builtin_bit_cast(bf16x8, bc2), acc[2], 0, 0, 0);
            acc[3] = __builtin_amdgcn_mfma_f32_32x32x16_bf16(
                         ah, __builtin_bit_cast(bf16x8, bc3), acc[3], 0, 0, 0);
            bc0 = nb0; bc1 = nb1; bc2 = nb2; bc3 = nb3;
        }
        {   // esq-fold chunk (dc==16, in nh0): B constant 1.0 in kd slots 0,1
            bf16x8 ah = __builtin_bit_cast(bf16x8, nh0);
#pragma unroll
            for (int tc = 0; tc < 4; ++tc)
                acc[tc] = __builtin_amdgcn_mfma_f32_32x32x16_bf16(
                              ah, bh_fold, acc[tc], 0, 0, 0);
        }
        // scan acc -> per-tc running top3
        int kb = kc * 32 + 4 * dhalf;
#pragma unroll
        for (int tc = 0; tc < 4; ++tc)
#pragma unroll
            for (int ri = 0; ri < 16; ++ri) {
                int kk = kb + (ri & 3) + 8 * (ri >> 2);
                ins3(v1s[tc], k1s[tc], v2s[tc], k2s[tc],
                     v3s[tc], k3s[tc], acc[tc][ri], kk);
            }
    }

    // merge lane^32 partner (same t, complementary k rows), store to LDS
#pragma unroll
    for (int tc = 0; tc < 4; ++tc) {
        float pv1 = __shfl_xor(v1s[tc], 32, 64); int pk1 = __shfl_xor(k1s[tc], 32, 64);
        float pv2 = __shfl_xor(v2s[tc], 32, 64); int pk2 = __shfl_xor(k2s[tc], 32, 64);
        float pv3 = __shfl_xor(v3s[tc], 32, 64); int pk3 = __shfl_xor(k3s[tc], 32, 64);
        ins3(v1s[tc], k1s[tc], v2s[tc], k2s[tc], v3s[tc], k3s[tc], pv1, pk1);
        ins3(v1s[tc], k1s[tc], v2s[tc], k2s[tc], v3s[tc], k3s[tc], pv2, pk2);
        ins3(v1s[tc], k1s[tc], v2s[tc], k2s[tc], v3s[tc], k3s[tc], pv3, pk3);
        if (dhalf == 0) {
            int base = ((w * 4 + tc) * 32 + (lane & 31)) * 3;
            redv[base]     = v1s[tc]; redk[base]     = k1s[tc];
            redv[base + 1] = v2s[tc]; redk[base + 1] = k2s[tc];
            redv[base + 2] = v3s[tc]; redk[base + 2] = k3s[tc];
        }
    }
    __syncthreads();

    // per-t reduce across 8 waves -> packed top3 + ||x||^2 to global
    if (tid < 128) {
        int t = tid, tc = t >> 5, m = t & 31;
        float v1 = -INFINITY, v2 = -INFINITY, v3 = -INFINITY;
        int k1 = 0, k2 = 0, k3 = 0;
#pragma unroll
        for (int ww = 0; ww < 8; ++ww) {
            int base = ((ww * 4 + tc) * 32 + m) * 3;
            ins3(v1, k1, v2, k2, v3, k3, redv[base], redk[base]);
            ins3(v1, k1, v2, k2, v3, k3, redv[base + 1], redk[base + 1]);
            ins3(v1, k1, v2, k2, v3, k3, redv[base + 2], redk[base + 2]);
        }
        float x2 = 0.f;
#pragma unroll
        for (int i = 0; i < 4; ++i) x2 += x2p[t + 128 * i];
        x2g[(size_t)tile * 128 + t] = x2;
        unsigned bits = (unsigned)k1 | ((unsigned)k2 << 10) | ((unsigned)k3 << 20);
        cand[(size_t)tile * 128 + t] =
            make_float4(v1, v2, v3, __int_as_float((int)bits));
    }
}

// --- K3: finish. grid 1024 x 256 thr, t-tile 64, 2 blocks/CU --------------
// reduce cand -> idx/loss (ties -> wave-parallel exact fp64 over top-3),
// gather E rows into LDS, write out0 [B,D,T] + idx.
__global__ __launch_bounds__(256) void finish_kernel(
        const float* __restrict__ X, const float* __restrict__ E,
        const float4* __restrict__ cand, const float* __restrict__ x2g,
        float* __restrict__ out0, float* __restrict__ loss,
        float* __restrict__ idxf_out) {
    extern __shared__ char smem[];
    float* q    = (float*)(smem + SM3_Q);    // [64][257]
    int*   idxs = (int*)(smem + SM3_IDX);
    int*   tiec = (int*)(smem + SM3_TIEC);
    uint2* tiel = (uint2*)(smem + SM3_TIEL);

    int tid = threadIdx.x;
    int lane = tid & 63;
    int w = tid >> 6;                        // 0..3
    int b = blockIdx.x >> 5;                 // 0..31
    int tg0 = (blockIdx.x & 31) << 6;
    size_t n0 = (size_t)blockIdx.x * 64;     // global token base

    if (tid == 0) tiec[0] = 0;
    __syncthreads();

    if (tid < 64) {
        int t = tid;
        float4 c = cand[n0 + t];
        int bits = __float_as_int(c.w);
        int k1 = bits & 1023, k2 = (bits >> 10) & 1023, k3 = (bits >> 20) & 1023;
        float dmin2 = 0.f;
        if (c.x - c.y < THR) {    // near-tie: defer exact fp64 refinement
            int slot = atomicAdd(tiec, 1);
            tiel[slot] = make_uint2(((unsigned)t << 10) | (unsigned)k1,
                                    ((unsigned)k2 << 16) | (unsigned)k3);
        } else {
            idxs[t] = k1;
            idxf_out[(size_t)b * T_SZ + tg0 + t] = (float)k1;
            dmin2 = x2g[n0 + t] - 2.0f * c.x;   // ||x||^2 - 2(x.e - esq/2)
        }
        float lsum = dmin2;
#pragma unroll
        for (int off = 32; off > 0; off >>= 1) lsum += __shfl_down(lsum, off, 64);
        if (tid == 0) atomicAdd(loss, lsum * (0.5f / (float)TOT));
    }
    __syncthreads();

    // wave-parallel exact refinement: one wave per tie, 64 lanes x 4 d each
    {
        int ntie = tiec[0];
        for (int e = w; e < ntie; e += 4) {
            uint2 pk = tiel[e];
            int t = pk.x >> 10;
            int k1 = pk.x & 1023, k2 = pk.y >> 16, k3 = pk.y & 1023;
            const float* e1 = E + (size_t)k1 * D_DIM;
            const float* e2 = E + (size_t)k2 * D_DIM;
            const float* e3 = E + (size_t)k3 * D_DIM;
            const float* xc = X + (size_t)b * ((size_t)D_DIM * T_SZ) + tg0 + t;
            int d0 = lane * 4;
            double d1 = 0.0, d2 = 0.0, d3 = 0.0;
#pragma unroll
            for (int u = 0; u < 4; ++u) {
                int d = d0 + u;
                double xd = (double)xc[(size_t)d * T_SZ];
                double u1 = xd - (double)e1[d];
                double u2 = xd - (double)e2[d];
                double u3 = xd - (double)e3[d];
                d1 += u1 * u1;
                d2 += u2 * u2;
                d3 += u3 * u3;
            }
#pragma unroll
            for (int off = 32; off > 0; off >>= 1) {
                d1 += __shfl_down(d1, off, 64);
                d2 += __shfl_down(d2, off, 64);
                d3 += __shfl_down(d3, off, 64);
            }
            if (lane == 0) {
                int kb = k1; double dm = d1;
                if (d2 < dm || (d2 == dm && k2 < kb)) { kb = k2; dm = d2; }
                if (d3 < dm || (d3 == dm && k3 < kb)) { kb = k3; dm = d3; }
                idxs[t] = kb;
                idxf_out[(size_t)b * T_SZ + tg0 + t] = (float)kb;
                atomicAdd(loss, (float)dm * (0.5f / (float)TOT));
            }
        }
    }
    __syncthreads();

    // gather E rows into q overlay (stride 257 -> conflict-free column reads)
    {
        for (int i = 0; i < 16; ++i) {
            int r = w * 16 + i;
            int row = idxs[r];
            const float* ep = E + (size_t)row * D_DIM;
#pragma unroll
            for (int u = 0; u < 4; ++u)
                q[r * 257 + lane + 64 * u] = ep[lane + 64 * u];
        }
    }
    __syncthreads();

    // write out0 [B,D,T]: lanes over t (coalesced 256B), LDS conflict-free
    {
        int t = tid & 63, dgrp = tid >> 6;
        size_t obase = (size_t)b * ((size_t)D_DIM * T_SZ) + tg0 + t;
#pragma unroll 8
        for (int j = 0; j < 64; ++j) {
            int d = dgrp * 64 + j;
            out0[obase + (size_t)d * T_SZ] = q[t * 257 + d];
        }
    }
}

extern "C" void kernel_launch(void* const* d_in, const int* in_sizes, int n_in,
                              void* d_out, int out_size, void* d_ws, size_t ws_size,
                              hipStream_t stream) {
    const float* X = (const float*)d_in[0];   // [32, 256, 2048] fp32
    const float* E = (const float*)d_in[1];   // [1024, 256] fp32
    float* out = (float*)d_out;
    float* loss = out + LOSS_OFF;
    float* idxf = out + IDX_OFF;

    unsigned short* Ehi = (unsigned short*)((char*)d_ws + WS_EHI);
    float*          x2g = (float*)((char*)d_ws + WS_X2);
    float4*        candp = (float4*)((char*)d_ws + WS_CAND);

    prepack_kernel<<<(32 * NDC * 64 + 255) / 256, 256, 0, stream>>>(E, Ehi, loss);
    argmin_kernel<<<512, 512, SM2_TOT, stream>>>(X, Ehi, candp, x2g);
    finish_kernel<<<1024, 256, SM3_TOT, stream>>>(X, E, candp, x2g, out, loss, idxf);
}